// Round 9
// baseline (50.106 us; speedup 1.0000x reference)
//
#include <hip/hip_runtime.h>
#include <hip/hip_bf16.h>
#include <math.h>

#define NBINS   1024
#define NPART   1024    // hist grid: 1024 blocks x 128 rows (2 waves x 64 rows)
#define LSTRIDE 72      // ushorts per bin-row: 144B, 16B-aligned slots

typedef __attribute__((ext_vector_type(8)))  short short8;   // 8 bf16 = 4 VGPR
typedef __attribute__((ext_vector_type(16))) float f32x16;   // MFMA 32x32 acc

// ws layout: gC[1024*1024] partials (4MB) | scalar (f32) | counter (i32).
// hist identical to R8 (16.5us verified) + block0 zeroing scalar/counter.
// Kernel 2 fuses reduce+finalize via the dispatch-order-safe last-block pattern.

__global__ __launch_bounds__(128, 2) void hist_kernel(const float* __restrict__ act,
                                                      float* __restrict__ gC,
                                                      float* __restrict__ scalar,
                                                      int* __restrict__ counter,
                                                      int rows)
{
    __shared__ ushort Phi_u[2][32][LSTRIDE];   // 9KB
    __shared__ ushort Plo_u[2][32][LSTRIDE];   // 9KB
    __shared__ float  C_lds[NBINS];            // 4KB

    const int tid  = threadIdx.x;
    const int wav  = tid >> 6;
    const int lane = tid & 63;

    // init for kernel 2 (kernel boundary orders this before reduce's atomics)
    if (blockIdx.x == 0 && tid == 0) { *scalar = 0.0f; *counter = 0; }

    const int row = blockIdx.x * 128 + tid;

    float v[10];
    float valid = 1.0f;
    if (row < rows) {
        const float2* a2 = (const float2*)(act + (size_t)row * 10);
        #pragma unroll
        for (int k = 0; k < 5; ++k) {
            float2 t = a2[k];
            v[2 * k] = t.x; v[2 * k + 1] = t.y;
        }
    } else {
        valid = 0.0f;
        #pragma unroll
        for (int k = 0; k < 10; ++k) v[k] = 0.0f;
    }

    // Product trees (f32). r=0 is the MSB of the 10-bit joint index.
    float hi[32], lo[32];
    {
        float t2[2], t4[4], t8[8], t16[16];
        t2[0] = valid * (1.0f - v[0]); t2[1] = valid * v[0];
        #pragma unroll
        for (int k = 0; k < 4; ++k)  t4[k]  = t2[k >> 1]  * ((k & 1) ? v[1] : 1.0f - v[1]);
        #pragma unroll
        for (int k = 0; k < 8; ++k)  t8[k]  = t4[k >> 1]  * ((k & 1) ? v[2] : 1.0f - v[2]);
        #pragma unroll
        for (int k = 0; k < 16; ++k) t16[k] = t8[k >> 1]  * ((k & 1) ? v[3] : 1.0f - v[3]);
        #pragma unroll
        for (int k = 0; k < 32; ++k) hi[k]  = t16[k >> 1] * ((k & 1) ? v[4] : 1.0f - v[4]);
    }
    {
        float t2[2], t4[4], t8[8], t16[16];
        t2[0] = 1.0f - v[5]; t2[1] = v[5];
        #pragma unroll
        for (int k = 0; k < 4; ++k)  t4[k]  = t2[k >> 1]  * ((k & 1) ? v[6] : 1.0f - v[6]);
        #pragma unroll
        for (int k = 0; k < 8; ++k)  t8[k]  = t4[k >> 1]  * ((k & 1) ? v[7] : 1.0f - v[7]);
        #pragma unroll
        for (int k = 0; k < 16; ++k) t16[k] = t8[k >> 1]  * ((k & 1) ? v[8] : 1.0f - v[8]);
        #pragma unroll
        for (int k = 0; k < 32; ++k) lo[k]  = t16[k >> 1] * ((k & 1) ? v[9] : 1.0f - v[9]);
    }

    // Stage as bf16; per instruction lanes hit banks (lane/2)%32 -> 2/bank = free.
    #pragma unroll
    for (int m = 0; m < 32; ++m) {
        __hip_bfloat16 bh = __float2bfloat16(hi[m]);
        __hip_bfloat16 bl = __float2bfloat16(lo[m]);
        Phi_u[wav][m][lane] = *(const ushort*)&bh;
        Plo_u[wav][m][lane] = *(const ushort*)&bl;
    }

    __syncthreads();

    // Phase 2: C(32x32) += Phi^T * Plo over this wave's 64 rows via 4 MFMAs.
    const int m  = lane & 31;
    const int kh = (lane >> 5) * 8;      // 0 or 8

    f32x16 acc = {};
    #pragma unroll
    for (int t = 0; t < 4; ++t) {
        const short8 a = *(const short8*)&Phi_u[wav][m][kh + 16 * t];  // 16B aligned
        const short8 b = *(const short8*)&Plo_u[wav][m][kh + 16 * t];
        acc = __builtin_amdgcn_mfma_f32_32x32x16_bf16(a, b, acc, 0, 0, 0);
    }

    // Merge 2 waves without atomics: wave1 stores, wave0 adds. 2/bank = free.
    if (wav == 1) {
        #pragma unroll
        for (int r = 0; r < 16; ++r)
            C_lds[r * 64 + lane] = acc[r];
    }
    __syncthreads();
    if (wav == 0) {
        #pragma unroll
        for (int r = 0; r < 16; ++r)
            C_lds[r * 64 + lane] += acc[r];
    }
    __syncthreads();

    // coalesced plain-store of the block's 4KB partial
    float4* dst4 = (float4*)(gC + (size_t)blockIdx.x * NBINS);
    const float4* src4 = (const float4*)C_lds;
    dst4[tid]       = src4[tid];
    dst4[tid + 128] = src4[tid + 128];
}

// Fused reduce + entropy + final sum (last-block pattern; no ordering assumptions).
// 32 blocks x 256 threads; block owns 32 bins completely.
__global__ __launch_bounds__(256) void reduce_kernel(const float* __restrict__ gC,
                                                     float* __restrict__ scalar,
                                                     int* __restrict__ counter,
                                                     float* __restrict__ out,
                                                     float invB)
{
    __shared__ float red[8][32];
    const int tid = threadIdx.x;
    const int g   = tid >> 5;            // 0..7 partial-group
    const int i   = tid & 31;            // bin within block
    const int bin = blockIdx.x * 32 + i;

    float s = 0.0f;
    for (int k = g; k < NPART; k += 8)   // wave = 2 partials x 32 bins: 128B coalesced
        s += gC[(size_t)k * NBINS + bin];
    red[g][i] = s;
    __syncthreads();

    if (tid < 32) {
        float t = 0.0f;
        #pragma unroll
        for (int k = 0; k < 8; ++k) t += red[k][tid];
        const float p = t * invB;
        float e = p * log2f(fmaxf(p, 1e-12f));    // sum p*log2(clip(p)) = -joint_h
        #pragma unroll
        for (int off = 16; off > 0; off >>= 1) e += __shfl_xor(e, off);
        if (tid == 0) {
            atomicAdd(scalar, e);                 // device-scope
            __threadfence();
            const int old = atomicAdd(counter, 1);
            if (old == 31) {                      // all 32 scalar-adds visible
                out[0] = atomicAdd(scalar, 0.0f); // atomic read of final sum
            }
        }
    }
}

extern "C" void kernel_launch(void* const* d_in, const int* in_sizes, int n_in,
                              void* d_out, int out_size, void* d_ws, size_t ws_size,
                              hipStream_t stream)
{
    const float* act = (const float*)d_in[0];
    const int rows = in_sizes[0] / 10;        // B = 131072
    float* gC      = (float*)d_ws;            // 1024 x 1024 block partials (4MB)
    float* scalar  = gC + (size_t)NPART * NBINS;
    int*   counter = (int*)(scalar + 1);

    hist_kernel<<<NPART, 128, 0, stream>>>(act, gC, scalar, counter, rows);
    reduce_kernel<<<32, 256, 0, stream>>>(gC, scalar, counter, (float*)d_out,
                                          1.0f / (float)rows);
}

// Round 10
// 16.273 us; speedup vs baseline: 3.0790x; 3.0790x over previous
//
#include <hip/hip_runtime.h>
#include <hip/hip_bf16.h>
#include <math.h>

#define NBINS   1024
#define NPART   512     // hist grid: 512 blocks x 2 batches x 128 rows
#define NCHUNK  32
#define PPC     16      // partials per chunk in reduce (NPART/NCHUNK)
#define LSTRIDE 72      // ushorts per bin-row: 144B, 16B-aligned slots

typedef __attribute__((ext_vector_type(8)))  short short8;   // 8 bf16 = 4 VGPR
typedef __attribute__((ext_vector_type(16))) float f32x16;   // MFMA 32x32 acc

// R8 shell (16.5us verified) + 2-batch register accumulation in hist.
// ws layout: gC[NPART*NBINS] partials (2MB) | g2[32*1024] chunk partials (128KB).
// No atomics anywhere; d_out written only by finalize (plain store).

__device__ __forceinline__ void make_trees(const float v[10], float valid,
                                           float hi[32], float lo[32])
{
    {
        float t2[2], t4[4], t8[8], t16[16];
        t2[0] = valid * (1.0f - v[0]); t2[1] = valid * v[0];
        #pragma unroll
        for (int k = 0; k < 4; ++k)  t4[k]  = t2[k >> 1]  * ((k & 1) ? v[1] : 1.0f - v[1]);
        #pragma unroll
        for (int k = 0; k < 8; ++k)  t8[k]  = t4[k >> 1]  * ((k & 1) ? v[2] : 1.0f - v[2]);
        #pragma unroll
        for (int k = 0; k < 16; ++k) t16[k] = t8[k >> 1]  * ((k & 1) ? v[3] : 1.0f - v[3]);
        #pragma unroll
        for (int k = 0; k < 32; ++k) hi[k]  = t16[k >> 1] * ((k & 1) ? v[4] : 1.0f - v[4]);
    }
    {
        float t2[2], t4[4], t8[8], t16[16];
        t2[0] = 1.0f - v[5]; t2[1] = v[5];
        #pragma unroll
        for (int k = 0; k < 4; ++k)  t4[k]  = t2[k >> 1]  * ((k & 1) ? v[6] : 1.0f - v[6]);
        #pragma unroll
        for (int k = 0; k < 8; ++k)  t8[k]  = t4[k >> 1]  * ((k & 1) ? v[7] : 1.0f - v[7]);
        #pragma unroll
        for (int k = 0; k < 16; ++k) t16[k] = t8[k >> 1]  * ((k & 1) ? v[8] : 1.0f - v[8]);
        #pragma unroll
        for (int k = 0; k < 32; ++k) lo[k]  = t16[k >> 1] * ((k & 1) ? v[9] : 1.0f - v[9]);
    }
}

__global__ __launch_bounds__(128, 2) void hist_kernel(const float* __restrict__ act,
                                                      float* __restrict__ gC,
                                                      int rows)
{
    __shared__ ushort Phi_u[2][32][LSTRIDE];   // 9KB
    __shared__ ushort Plo_u[2][32][LSTRIDE];   // 9KB
    __shared__ float  C_lds[NBINS];            // 4KB

    const int tid  = threadIdx.x;
    const int wav  = tid >> 6;
    const int lane = tid & 63;

    const int r0 = blockIdx.x * 256 + tid;     // batch 0 row
    const int r1 = r0 + 128;                   // batch 1 row

    // Prefetch BOTH batches' rows up front (hides HBM latency at low occupancy).
    float v0[10], v1[10];
    float valid0 = 1.0f, valid1 = 1.0f;
    if (r0 < rows) {
        const float2* a2 = (const float2*)(act + (size_t)r0 * 10);
        #pragma unroll
        for (int k = 0; k < 5; ++k) { float2 t = a2[k]; v0[2*k] = t.x; v0[2*k+1] = t.y; }
    } else {
        valid0 = 0.0f;
        #pragma unroll
        for (int k = 0; k < 10; ++k) v0[k] = 0.0f;
    }
    if (r1 < rows) {
        const float2* a2 = (const float2*)(act + (size_t)r1 * 10);
        #pragma unroll
        for (int k = 0; k < 5; ++k) { float2 t = a2[k]; v1[2*k] = t.x; v1[2*k+1] = t.y; }
    } else {
        valid1 = 0.0f;
        #pragma unroll
        for (int k = 0; k < 10; ++k) v1[k] = 0.0f;
    }

    const int m  = lane & 31;
    const int kh = (lane >> 5) * 8;      // 0 or 8
    f32x16 acc = {};

    // ---- batch 0 ----
    {
        float hi[32], lo[32];
        make_trees(v0, valid0, hi, lo);
        #pragma unroll
        for (int q = 0; q < 32; ++q) {
            __hip_bfloat16 bh = __float2bfloat16(hi[q]);
            __hip_bfloat16 bl = __float2bfloat16(lo[q]);
            Phi_u[wav][q][lane] = *(const ushort*)&bh;
            Plo_u[wav][q][lane] = *(const ushort*)&bl;
        }
        __syncthreads();
        #pragma unroll
        for (int t = 0; t < 4; ++t) {
            const short8 a = *(const short8*)&Phi_u[wav][m][kh + 16 * t];
            const short8 b = *(const short8*)&Plo_u[wav][m][kh + 16 * t];
            acc = __builtin_amdgcn_mfma_f32_32x32x16_bf16(a, b, acc, 0, 0, 0);
        }
        __syncthreads();   // all waves done reading before restage
    }
    // ---- batch 1 (accumulates into same acc) ----
    {
        float hi[32], lo[32];
        make_trees(v1, valid1, hi, lo);
        #pragma unroll
        for (int q = 0; q < 32; ++q) {
            __hip_bfloat16 bh = __float2bfloat16(hi[q]);
            __hip_bfloat16 bl = __float2bfloat16(lo[q]);
            Phi_u[wav][q][lane] = *(const ushort*)&bh;
            Plo_u[wav][q][lane] = *(const ushort*)&bl;
        }
        __syncthreads();
        #pragma unroll
        for (int t = 0; t < 4; ++t) {
            const short8 a = *(const short8*)&Phi_u[wav][m][kh + 16 * t];
            const short8 b = *(const short8*)&Plo_u[wav][m][kh + 16 * t];
            acc = __builtin_amdgcn_mfma_f32_32x32x16_bf16(a, b, acc, 0, 0, 0);
        }
    }

    // Merge 2 waves without atomics: wave1 stores, wave0 adds. 2/bank = free.
    if (wav == 1) {
        #pragma unroll
        for (int r = 0; r < 16; ++r)
            C_lds[r * 64 + lane] = acc[r];
    }
    __syncthreads();
    if (wav == 0) {
        #pragma unroll
        for (int r = 0; r < 16; ++r)
            C_lds[r * 64 + lane] += acc[r];
    }
    __syncthreads();

    // coalesced plain-store of the block's 4KB partial
    float4* dst4 = (float4*)(gC + (size_t)blockIdx.x * NBINS);
    const float4* src4 = (const float4*)C_lds;
    dst4[tid]       = src4[tid];
    dst4[tid + 128] = src4[tid + 128];
}

// Sum 512 block-partials -> 32 chunk-partials. 128 blocks x 256 threads.
__global__ __launch_bounds__(256) void reduce_kernel(const float* __restrict__ gC,
                                                     float* __restrict__ g2)
{
    const int chunk = blockIdx.x >> 2;                    // 0..31
    const int bin   = (blockIdx.x & 3) * 256 + threadIdx.x;
    const float* p  = gC + (size_t)chunk * PPC * NBINS + bin;
    float s = 0.0f;
    #pragma unroll
    for (int k = 0; k < PPC; ++k) s += p[k * NBINS];      // coalesced across threads
    g2[chunk * NBINS + bin] = s;
}

__global__ __launch_bounds__(256) void finalize_kernel(const float* __restrict__ g2,
                                                       float* __restrict__ out,
                                                       float invB)
{
    __shared__ float red[4];
    const int tid = threadIdx.x;

    float4 acc = make_float4(0.f, 0.f, 0.f, 0.f);
    #pragma unroll
    for (int s = 0; s < NCHUNK; ++s) {
        const float4 t = *(const float4*)&g2[s * NBINS + tid * 4];
        acc.x += t.x; acc.y += t.y; acc.z += t.z; acc.w += t.w;
    }

    float s = 0.0f;
    const float b[4] = {acc.x, acc.y, acc.z, acc.w};
    #pragma unroll
    for (int k = 0; k < 4; ++k) {
        const float p  = b[k] * invB;
        const float ps = fmaxf(p, 1e-12f);
        s += p * log2f(ps);   // out = sum p*log2(clip(p)) = -joint_h
    }
    #pragma unroll
    for (int off = 32; off > 0; off >>= 1) s += __shfl_down(s, off);
    if ((tid & 63) == 0) red[tid >> 6] = s;
    __syncthreads();
    if (tid == 0) out[0] = red[0] + red[1] + red[2] + red[3];
}

extern "C" void kernel_launch(void* const* d_in, const int* in_sizes, int n_in,
                              void* d_out, int out_size, void* d_ws, size_t ws_size,
                              hipStream_t stream)
{
    const float* act = (const float*)d_in[0];
    const int rows = in_sizes[0] / 10;        // B = 131072 = 512 * 256
    float* gC = (float*)d_ws;                 // NPART x NBINS partials (2MB)
    float* g2 = gC + (size_t)NPART * NBINS;   // 32 x 1024 chunk partials (128KB)

    hist_kernel<<<NPART, 128, 0, stream>>>(act, gC, rows);
    reduce_kernel<<<128, 256, 0, stream>>>(gC, g2);
    finalize_kernel<<<1, 256, 0, stream>>>(g2, (float*)d_out, 1.0f / (float)rows);
}